// Round 5
// baseline (363.600 us; speedup 1.0000x reference)
//
#include <hip/hip_runtime.h>
#include <hip/hip_bf16.h>
#include <math.h>

#define L_SEQ 2048
#define NB 4
#define DMODEL 256
#define NH 8
#define DHEAD 32
#define NROW (NB*L_SEQ)

typedef __attribute__((ext_vector_type(8))) short short8;
typedef __attribute__((ext_vector_type(4))) float f32x4;

__device__ __forceinline__ short f2bf(float f) {
    union { float f; unsigned u; } x; x.f = f;
    unsigned r = x.u + 0x7fff + ((x.u >> 16) & 1);
    return (short)(r >> 16);
}
__device__ __forceinline__ short8 zero8() {
    short8 z;
    #pragma unroll
    for (int i = 0; i < 8; ++i) z[i] = 0;
    return z;
}

// ---------------- sinusoidal positional encoding ----------------
__global__ void pe_kernel(float* __restrict__ pe) {
    int idx = blockIdx.x*256 + threadIdx.x;      // 2048*128 total
    int l = idx >> 7, m = idx & 127;
    double ang = (double)l * exp((double)m * (-9.210340371976184/128.0));
    pe[l*DMODEL + 2*m]   = (float)sin(ang);
    pe[l*DMODEL + 2*m+1] = (float)cos(ang);
}

// ---------------- layernorm (one wave per row) ----------------
__global__ void ln_kernel(const float* __restrict__ x, const float* __restrict__ gamma,
                          const float* __restrict__ beta, float* __restrict__ xn) {
    int lane = threadIdx.x & 63;
    int row  = blockIdx.x*4 + (threadIdx.x >> 6);
    const float4 a = *(const float4*)(x + (size_t)row*DMODEL + lane*4);
    float s  = a.x+a.y+a.z+a.w;
    float s2 = a.x*a.x+a.y*a.y+a.z*a.z+a.w*a.w;
    #pragma unroll
    for (int o = 32; o; o >>= 1) { s += __shfl_xor(s,o); s2 += __shfl_xor(s2,o); }
    float mu  = s * (1.f/DMODEL);
    float var = s2 * (1.f/DMODEL) - mu*mu;
    float rst = rsqrtf(var + 1e-3f);
    const float4 g  = *(const float4*)(gamma + lane*4);
    const float4 bt = *(const float4*)(beta  + lane*4);
    float4 o;
    o.x = (a.x-mu)*rst*g.x + bt.x;
    o.y = (a.y-mu)*rst*g.y + bt.y;
    o.z = (a.z-mu)*rst*g.z + bt.z;
    o.w = (a.w-mu)*rst*g.w + bt.w;
    *(float4*)(xn + (size_t)row*DMODEL + lane*4) = o;
}

// ---------------- fp32 GEMM core (128x128 tile, 8x8 micro) ----------------
__device__ __forceinline__ void gemm_core(const float* __restrict__ A,
                                          const float* __restrict__ W,
                                          int row0, int col0, float acc[8][8]) {
    __shared__ float As[8][136];
    __shared__ float Ws[8][136];
    const int t  = threadIdx.x;
    const int tx = t & 15, ty = t >> 4;
    #pragma unroll
    for (int i = 0; i < 8; ++i)
        #pragma unroll
        for (int j = 0; j < 8; ++j) acc[i][j] = 0.f;

    const int ar = t >> 1, ac4 = t & 1;
    const int wr = t >> 5, wc4 = t & 31;

    for (int k0 = 0; k0 < 256; k0 += 8) {
        float4 av = *(const float4*)(A + (size_t)(row0+ar)*256 + k0 + ac4*4);
        As[ac4*4+0][ar] = av.x;
        As[ac4*4+1][ar] = av.y;
        As[ac4*4+2][ar] = av.z;
        As[ac4*4+3][ar] = av.w;
        *(float4*)&Ws[wr][wc4*4] = *(const float4*)(W + (size_t)(k0+wr)*256 + col0 + wc4*4);
        __syncthreads();
        #pragma unroll
        for (int kk = 0; kk < 8; ++kk) {
            float a8[8], b8[8];
            *(float4*)&a8[0] = *(const float4*)&As[kk][ty*8];
            *(float4*)&a8[4] = *(const float4*)&As[kk][ty*8+4];
            *(float4*)&b8[0] = *(const float4*)&Ws[kk][tx*8];
            *(float4*)&b8[4] = *(const float4*)&Ws[kk][tx*8+4];
            #pragma unroll
            for (int i = 0; i < 8; ++i)
                #pragma unroll
                for (int j = 0; j < 8; ++j)
                    acc[i][j] += a8[i]*b8[j];
        }
        __syncthreads();
    }
}

// ---------------- projections -> bf16 (qu = q+u, qv = q+v_bias, k, v, p) ----------------
__global__ __launch_bounds__(256)
void proj_kernel(const float* __restrict__ xn, const float* __restrict__ pe,
                 const float* __restrict__ Wq, const float* __restrict__ bq,
                 const float* __restrict__ Wk, const float* __restrict__ bk,
                 const float* __restrict__ Wv, const float* __restrict__ bv,
                 const float* __restrict__ Wp,
                 const float* __restrict__ ub, const float* __restrict__ vb,
                 short* __restrict__ qu, short* __restrict__ qv,
                 short* __restrict__ kb, short* __restrict__ vbuf,
                 short* __restrict__ pbuf) {
    const int z = blockIdx.z;
    const float* A; const float* W; int M;
    switch (z) {
        case 0:  A = xn; W = Wq; M = NROW;  break;
        case 1:  A = xn; W = Wk; M = NROW;  break;
        case 2:  A = xn; W = Wv; M = NROW;  break;
        default: A = pe; W = Wp; M = L_SEQ; break;
    }
    const int row0 = blockIdx.x * 128;
    if (row0 >= M) return;
    const int col0 = blockIdx.y * 128;
    float acc[8][8];
    gemm_core(A, W, row0, col0, acc);

    const int t = threadIdx.x;
    const int tx = t & 15, ty = t >> 4;
    #pragma unroll
    for (int i = 0; i < 8; ++i) {
        const int rr = row0 + ty*8 + i;
        #pragma unroll
        for (int j = 0; j < 8; ++j) {
            const int cc = col0 + tx*8 + j;
            const float a = acc[i][j];
            const size_t idx = (size_t)rr*DMODEL + cc;
            if (z == 0) {
                const float base = a + bq[cc];
                qu[idx] = f2bf(base + ub[cc]);
                qv[idx] = f2bf(base + vb[cc]);
            } else if (z == 1) {
                kb[idx] = f2bf(a + bk[cc]);
            } else if (z == 2) {
                vbuf[idx] = f2bf(a + bv[cc]);
            } else {
                pbuf[idx] = f2bf(a);
            }
        }
    }
}

// ---------------- final out GEMM (fp32) ----------------
__global__ __launch_bounds__(256)
void gemm_kernel(const float* __restrict__ A, const float* __restrict__ W,
                 const float* __restrict__ bias, float* __restrict__ C, int M) {
    const int row0 = blockIdx.x * 128;
    if (row0 >= M) return;
    const int col0 = blockIdx.y * 128;
    float acc[8][8];
    gemm_core(A, W, row0, col0, acc);
    const int t = threadIdx.x;
    const int tx = t & 15, ty = t >> 4;
    #pragma unroll
    for (int i = 0; i < 8; ++i) {
        const int rr = row0 + ty*8 + i;
        #pragma unroll
        for (int j4 = 0; j4 < 2; ++j4) {
            const int cc = col0 + tx*8 + j4*4;
            float4 o;
            o.x = acc[i][j4*4+0] + bias[cc+0];
            o.y = acc[i][j4*4+1] + bias[cc+1];
            o.z = acc[i][j4*4+2] + bias[cc+2];
            o.w = acc[i][j4*4+3] + bias[cc+3];
            *(float4*)(C + (size_t)rr*256 + cc) = o;
        }
    }
}

// ---------------- V transpose: v[b,l,h,d] -> vT[b,h,d,l] ----------------
__global__ __launch_bounds__(256)
void vtrans_kernel(const short* __restrict__ v, short* __restrict__ vT) {
    const int l0 = blockIdx.x * 64;
    const int h  = blockIdx.y;
    const int b  = blockIdx.z;
    const int t  = threadIdx.x;
    __shared__ short s[32][72];
    const int r = t & 63, c8 = (t >> 6) * 8;
    short8 val = *(const short8*)(v + ((size_t)(b*L_SEQ + l0 + r))*DMODEL + h*DHEAD + c8);
    #pragma unroll
    for (int j = 0; j < 8; ++j) s[c8+j][r] = val[j];
    __syncthreads();
    const int d = t >> 3, l8 = (t & 7) * 8;
    *(short8*)(vT + (((size_t)((b*NH + h)*DHEAD + d))*L_SEQ) + l0 + l8) = *(const short8*)&s[d][l8];
}

// ---------------- fused MFMA attention, swapped-operand, BARRIER-FREE ----------------
// Block = 256 threads (4 waves), one (b, h, 64-row q-tile). Every LDS structure is
// wave-private: sT[w][17][84] holds T rows 16w..16w+15 (unshifted pos-MFMA) plus the
// boundary row 16w+16 (shifted pos-MFMA, B = Qv rows +1, lc==15 lanes store). Wave w's
// gather only touches jj in [48-16w, 126-16w] (width 79) -> 5 pos-MFMA per set, col =
// jj - (48-16w). sPk rows are wave-private too. No __syncthreads in the whole kernel;
// intra-wave DS ordering + explicit lgkmcnt fences. All global loads float across the
// softmax (no barrier-forced vmcnt(0) drains). 31KB LDS -> 4 blocks/CU, grid fully resident.
__global__ __launch_bounds__(256, 4)
void attn_mfma_kernel(const short* __restrict__ qu, const short* __restrict__ qv,
                      const short* __restrict__ kb, const short* __restrict__ pb,
                      const short* __restrict__ vT, float* __restrict__ ctx) {
    const int q0 = blockIdx.x * 64;
    const int h  = blockIdx.y;
    const int b  = blockIdx.z;
    const int t  = threadIdx.x;
    const int w  = t >> 6;
    const int l  = t & 63;
    const int lc = l & 15;
    const int lg = l >> 4;

    __shared__ float    sT[4][17][84];  // per-wave: rows 0..15 = T[16w+lc], row 16 = boundary
    __shared__ unsigned sPk[64][32];    // P bf16-pairs, XOR-swizzled; reused as ctx tile

    // B-fragments: Q rows 16w+lc (wave-own), k = lg*8..+8, resident all tiles
    const size_t qrow = ((size_t)(b*L_SEQ + q0 + 16*w + lc))*DMODEL + h*DHEAD + lg*8;
    const short8 aqu = *(const short8*)(qu + qrow);
    const short8 aqv = *(const short8*)(qv + qrow);
    // shifted Qv (rows q0+16w+lc+1) for the per-wave boundary row (col lc=15 <-> row 16w+16)
    short8 aqv_sh = zero8();
    {
        const int r2 = q0 + 16*w + lc + 1;
        if (r2 < L_SEQ)
            aqv_sh = *(const short8*)(qv + ((size_t)(b*L_SEQ + r2))*DMODEL + h*DHEAD + lg*8);
    }

    float m_r = -3.0e38f, l_r = 0.f;
    f32x4 acc0 = {0.f,0.f,0.f,0.f}, acc1 = {0.f,0.f,0.f,0.f};

    const short* kbase = kb + ((size_t)(b*L_SEQ))*DMODEL + h*DHEAD;
    const short* pbase = pb + h*DHEAD;
    const short* vbase = vT + ((size_t)((b*NH + h)*DHEAD))*L_SEQ;
    const f32x4 zf = {0.f, 0.f, 0.f, 0.f};
    const float KSC = 0.0625f * 1.44269504088896340736f;  // (1/16)*log2(e)

    // ptilde loader for wave-window slot cc at tile k0n: jj = 16*(cc+3-w)+lc (A-row)
    auto loadP = [&](int k0n, int cc) -> short8 {
        const int rho = (k0n - q0 - 65) + 16*(cc + 3 - w) + lc;
        if (rho == -1) return zero8();
        const int pr = rho + (rho < 0 ? (L_SEQ+1) : 0);
        return *(const short8*)(pbase + (size_t)pr*DMODEL + lg*8);
    };

    // persistent A-fragments
    short8 kfrag[4], pfrag[5];
    #pragma unroll
    for (int ct = 0; ct < 4; ++ct)
        kfrag[ct] = *(const short8*)(kbase + (size_t)(ct*16 + lc)*DMODEL + lg*8);
    #pragma unroll
    for (int cc = 0; cc < 5; ++cc) pfrag[cc] = loadP(0, cc);

    const int qi   = 16*w + lc;
    const int colc = 4*lg + 15 - lc;     // gather col = 16*ct + colc + r
    const int swkey = lc & 7;

    for (int k0 = 0; k0 < L_SEQ; k0 += 64) {
        const int diff = k0 - q0;

        // ---- content: S^T tiles (A = K, B = Qu) ----
        f32x4 cts[4];
        #pragma unroll
        for (int ct = 0; ct < 4; ++ct)
            cts[ct] = __builtin_amdgcn_mfma_f32_16x16x32_bf16(kfrag[ct], aqu, zf, 0, 0, 0);

        // ---- pos band: unshifted (rows lc) + shifted (boundary row 16, lc==15 lanes) ----
        #pragma unroll
        for (int cc = 0; cc < 5; ++cc) {
            f32x4 tt = __builtin_amdgcn_mfma_f32_16x16x32_bf16(pfrag[cc], aqv, zf, 0, 0, 0);
            *(f32x4*)&sT[w][lc][16*cc + 4*lg] = tt;
            f32x4 tt2 = __builtin_amdgcn_mfma_f32_16x16x32_bf16(pfrag[cc], aqv_sh, zf, 0, 0, 0);
            if (lc == 15) *(f32x4*)&sT[w][16][16*cc + 4*lg] = tt2;
        }

        // ---- rotate p-window (slide 64 = 4 slots) + prefetch next tile ----
        pfrag[0] = pfrag[4];
        if (k0 + 64 < L_SEQ) {
            #pragma unroll
            for (int ct = 0; ct < 4; ++ct)
                kfrag[ct] = *(const short8*)(kbase + (size_t)(k0 + 64 + ct*16 + lc)*DMODEL + lg*8);
            #pragma unroll
            for (int cc = 1; cc < 5; ++cc) pfrag[cc] = loadP(k0 + 64, cc);
        }
        // V fragments for the CURRENT tile (consumed after softmax)
        short8 vfrag[2][2];
        #pragma unroll
        for (int dt = 0; dt < 2; ++dt)
            #pragma unroll
            for (int kc = 0; kc < 2; ++kc)
                vfrag[dt][kc] = *(const short8*)(vbase + (size_t)(16*dt + lc)*L_SEQ + k0 + kc*32 + lg*8);

        asm volatile("s_waitcnt lgkmcnt(0)" ::: "memory");  // sT writes visible (intra-wave)

        // ---- rel-shift gather + combine: read sT[w][lc+up][16ct+colc+r] ----
        float sc[4][4];
        const int cthr = 17 - diff + 16*w;   // up = (col >= cthr)
        if (cthr > 78) {
            const float* rowp = &sT[w][lc][0];
            #pragma unroll
            for (int ct = 0; ct < 4; ++ct)
                #pragma unroll
                for (int r = 0; r < 4; ++r)
                    sc[ct][r] = (cts[ct][r] + rowp[16*ct + colc + r]) * KSC;
        } else if (cthr <= 0) {
            const float* rowp = &sT[w][lc+1][0];
            #pragma unroll
            for (int ct = 0; ct < 4; ++ct)
                #pragma unroll
                for (int r = 0; r < 4; ++r)
                    sc[ct][r] = (cts[ct][r] + rowp[16*ct + colc + r]) * KSC;
        } else {
            #pragma unroll
            for (int ct = 0; ct < 4; ++ct)
                #pragma unroll
                for (int r = 0; r < 4; ++r) {
                    const int col = 16*ct + colc + r;
                    const int up = (col >= cthr) ? 1 : 0;
                    sc[ct][r] = (cts[ct][r] + sT[w][lc + up][col]) * KSC;
                }
        }

        // ---- softmax: lane owns row qi; in-reg reduce + 2 shfls ----
        float mx = sc[0][0];
        #pragma unroll
        for (int ct = 0; ct < 4; ++ct)
            #pragma unroll
            for (int r = 0; r < 4; ++r) mx = fmaxf(mx, sc[ct][r]);
        mx = fmaxf(mx, __shfl_xor(mx, 16));
        mx = fmaxf(mx, __shfl_xor(mx, 32));
        const float mn = fmaxf(m_r, mx);
        float ts = 0.f;
        #pragma unroll
        for (int ct = 0; ct < 4; ++ct)
            #pragma unroll
            for (int r = 0; r < 4; ++r) { sc[ct][r] = exp2f(sc[ct][r] - mn); ts += sc[ct][r]; }
        ts += __shfl_xor(ts, 16);
        ts += __shfl_xor(ts, 32);
        const float alpha = exp2f(m_r - mn);
        m_r = mn;
        l_r = l_r*alpha + ts;

        // ---- pack P -> sPk (bf16 pairs, XOR-block swizzle; wave-private rows) ----
        #pragma unroll
        for (int ct = 0; ct < 4; ++ct) {
            unsigned lo, hi;
            asm("v_cvt_pk_bf16_f32 %0, %1, %2" : "=v"(lo) : "v"(sc[ct][0]), "v"(sc[ct][1]));
            asm("v_cvt_pk_bf16_f32 %0, %1, %2" : "=v"(hi) : "v"(sc[ct][2]), "v"(sc[ct][3]));
            const int kbi = 2*ct + (lg >> 1);
            const int idx = ((kbi ^ swkey) << 2) + 2*(lg & 1);
            *(uint2*)&sPk[qi][idx] = make_uint2(lo, hi);
        }
        #pragma unroll
        for (int r = 0; r < 4; ++r) { acc0[r] *= alpha; acc1[r] *= alpha; }

        asm volatile("s_waitcnt lgkmcnt(0)" ::: "memory");  // sPk writes visible (intra-wave)

        // ---- PV: ctx^T += V^T . P ----
        #pragma unroll
        for (int kc = 0; kc < 2; ++kc) {
            const int idx = ((4*kc + lg) ^ swkey) << 2;
            const short8 bp = *(const short8*)&sPk[qi][idx];
            acc0 = __builtin_amdgcn_mfma_f32_16x16x32_bf16(vfrag[0][kc], bp, acc0, 0, 0, 0);
            acc1 = __builtin_amdgcn_mfma_f32_16x16x32_bf16(vfrag[1][kc], bp, acc1, 0, 0, 0);
        }
    }

    // ---- epilogue: transpose ctx^T -> ctx through sPk space (wave-private rows) ----
    asm volatile("s_waitcnt lgkmcnt(0)" ::: "memory");
    float* sCt = (float*)&sPk[0][0];   // [64][32] f32 view
    const float inv = 1.f / l_r;
    {
        f32x4 o0, o1;
        #pragma unroll
        for (int r = 0; r < 4; ++r) { o0[r] = acc0[r]*inv; o1[r] = acc1[r]*inv; }
        *(f32x4*)&sCt[qi*32 + 4*lg]      = o0;
        *(f32x4*)&sCt[qi*32 + 16 + 4*lg] = o1;
    }
    asm volatile("s_waitcnt lgkmcnt(0)" ::: "memory");
    const int rr = 16*w + (l >> 2);
    const int c0 = (l & 3) * 8;
    float4 o0 = *(float4*)&sCt[rr*32 + c0];
    float4 o1 = *(float4*)&sCt[rr*32 + c0 + 4];
    float* orow = ctx + ((size_t)(b*L_SEQ + q0 + rr))*DMODEL + h*DHEAD + c0;
    *(float4*)orow     = o0;
    *(float4*)(orow+4) = o1;
}

extern "C" void kernel_launch(void* const* d_in, const int* in_sizes, int n_in,
                              void* d_out, int out_size, void* d_ws, size_t ws_size,
                              hipStream_t stream) {
    (void)in_sizes; (void)n_in; (void)out_size; (void)ws_size;
    const float* x     = (const float*)d_in[0];
    const float* gamma = (const float*)d_in[1];
    const float* beta  = (const float*)d_in[2];
    const float* Wq    = (const float*)d_in[3];
    const float* bq    = (const float*)d_in[4];
    const float* Wk    = (const float*)d_in[5];
    const float* bk    = (const float*)d_in[6];
    const float* Wv    = (const float*)d_in[7];
    const float* bv    = (const float*)d_in[8];
    const float* Wp    = (const float*)d_in[9];
    const float* ub    = (const float*)d_in[10];
    const float* vb    = (const float*)d_in[11];
    const float* Wo    = (const float*)d_in[12];
    const float* bo    = (const float*)d_in[13];
    float* out = (float*)d_out;

    char* wsb = (char*)d_ws;
    float* ctx = (float*)wsb;                                   // 8192*256 f32 (aliases xn)
    float* xn  = ctx;
    float* pe  = (float*)(wsb + (size_t)8388608);               // 2048*256 f32
    short* qu  = (short*)(wsb + (size_t)8388608 + 2097152);     // bf16 buffers
    short* qv  = qu + (size_t)NROW*DMODEL;
    short* kbf = qv + (size_t)NROW*DMODEL;
    short* vbf = kbf + (size_t)NROW*DMODEL;
    short* vT  = vbf + (size_t)NROW*DMODEL;
    short* pbf = vT  + (size_t)NROW*DMODEL;                     // 2048*256 bf16

    pe_kernel<<<1024, 256, 0, stream>>>(pe);
    ln_kernel<<<2048, 256, 0, stream>>>(x, gamma, beta, xn);
    proj_kernel<<<dim3(64,2,4), 256, 0, stream>>>(xn, pe, Wq, bq, Wk, bk, Wv, bv, Wp,
                                                  ub, vb, qu, qv, kbf, vbf, pbf);
    vtrans_kernel<<<dim3(32,8,4), 256, 0, stream>>>(vbf, vT);
    attn_mfma_kernel<<<dim3(32,8,4), 256, 0, stream>>>(qu, qv, kbf, pbf, vT, ctx);
    gemm_kernel<<<dim3(64,2,1), 256, 0, stream>>>(ctx, Wo, bo, out, NROW);
}

// Round 6
// 280.347 us; speedup vs baseline: 1.2970x; 1.2970x over previous
//
#include <hip/hip_runtime.h>
#include <hip/hip_bf16.h>
#include <math.h>

#define L_SEQ 2048
#define NB 4
#define DMODEL 256
#define NH 8
#define DHEAD 32
#define NROW (NB*L_SEQ)

typedef __attribute__((ext_vector_type(8))) short short8;
typedef __attribute__((ext_vector_type(4))) float f32x4;

__device__ __forceinline__ float bf2f(short v) {
    union { unsigned u; float f; } x; x.u = ((unsigned)(unsigned short)v) << 16; return x.f;
}
__device__ __forceinline__ short f2bf(float f) {
    union { float f; unsigned u; } x; x.f = f;
    unsigned r = x.u + 0x7fff + ((x.u >> 16) & 1);
    return (short)(r >> 16);
}
__device__ __forceinline__ short8 zero8() {
    short8 z;
    #pragma unroll
    for (int i = 0; i < 8; ++i) z[i] = 0;
    return z;
}

// ---------------- sinusoidal positional encoding (bf16) ----------------
__global__ void pe_kernel(short* __restrict__ peb) {
    int idx = blockIdx.x*256 + threadIdx.x;      // 2048*128 total
    int l = idx >> 7, m = idx & 127;
    double ang = (double)l * exp((double)m * (-9.210340371976184/128.0));
    unsigned s = (unsigned)(unsigned short)f2bf((float)sin(ang));
    unsigned c = (unsigned)(unsigned short)f2bf((float)cos(ang));
    *(unsigned*)(peb + l*DMODEL + 2*m) = s | (c << 16);
}

// ---------------- layernorm (one wave per row) -> bf16 ----------------
__global__ void ln_kernel(const float* __restrict__ x, const float* __restrict__ gamma,
                          const float* __restrict__ beta, short* __restrict__ xnb) {
    int lane = threadIdx.x & 63;
    int row  = blockIdx.x*4 + (threadIdx.x >> 6);
    const float4 a = *(const float4*)(x + (size_t)row*DMODEL + lane*4);
    float s  = a.x+a.y+a.z+a.w;
    float s2 = a.x*a.x+a.y*a.y+a.z*a.z+a.w*a.w;
    #pragma unroll
    for (int o = 32; o; o >>= 1) { s += __shfl_xor(s,o); s2 += __shfl_xor(s2,o); }
    float mu  = s * (1.f/DMODEL);
    float var = s2 * (1.f/DMODEL) - mu*mu;
    float rst = rsqrtf(var + 1e-3f);
    const float4 g  = *(const float4*)(gamma + lane*4);
    const float4 bt = *(const float4*)(beta  + lane*4);
    short4 o;
    o.x = f2bf((a.x-mu)*rst*g.x + bt.x);
    o.y = f2bf((a.y-mu)*rst*g.y + bt.y);
    o.z = f2bf((a.z-mu)*rst*g.z + bt.z);
    o.w = f2bf((a.w-mu)*rst*g.w + bt.w);
    *(short4*)(xnb + (size_t)row*DMODEL + lane*4) = o;
}

// ---------------- weight transpose+convert: W[k][n] f32 -> WT[n][k] bf16 ----------------
__global__ __launch_bounds__(256)
void wcvt_kernel(const float* __restrict__ W0, const float* __restrict__ W1,
                 const float* __restrict__ W2, const float* __restrict__ W3,
                 short* __restrict__ WT) {
    const float* W = (blockIdx.z==0)?W0:(blockIdx.z==1)?W1:(blockIdx.z==2)?W2:W3;
    short* O = WT + (size_t)blockIdx.z*65536;
    __shared__ float s[64][65];
    const int k0 = blockIdx.x*64, n0 = blockIdx.y*64;
    const int c = threadIdx.x & 63, r4 = threadIdx.x >> 6;
    #pragma unroll
    for (int i = 0; i < 16; ++i) {
        int r = r4 + 4*i;
        s[c][r] = W[(size_t)(k0+r)*256 + n0 + c];
    }
    __syncthreads();
    #pragma unroll
    for (int i = 0; i < 16; ++i) {
        int rn = r4 + 4*i;
        O[(size_t)(n0+rn)*256 + k0 + c] = f2bf(s[rn][c]);
    }
}

// ---------------- bf16 MFMA projections: C = A @ W (+bias) ----------------
// 416 blocks: bid<384 -> z=bid>>7 (0=q,1=k,2=v), rb=bid&127 over 8192 rows;
// else z=3 (p), rb over 2048 rows. Block = 4 waves, wave = 16 rows x 256 cols,
// 16 col-tiles x 8 k-steps = 128 MFMA. A-frags held; B-frags streamed from L2.
__global__ __launch_bounds__(256, 2)
void projmm_kernel(const short* __restrict__ xnb, const short* __restrict__ peb,
                   const short* __restrict__ WT,
                   const float* __restrict__ bq, const float* __restrict__ bk,
                   const float* __restrict__ bv,
                   short* __restrict__ q, short* __restrict__ kb,
                   short* __restrict__ vbuf, short* __restrict__ pbuf) {
    const int bid = blockIdx.x;
    int z, rb;
    if (bid < 384) { z = bid >> 7; rb = bid & 127; }
    else           { z = 3;        rb = bid - 384; }
    const short* A = (z == 3) ? peb : xnb;
    const short* W = WT + (size_t)z*65536;
    const int t = threadIdx.x;
    const int w = t >> 6, l = t & 63, lc = l & 15, lg = l >> 4;
    const int m0 = rb*64 + 16*w;

    short8 afr[8];
    #pragma unroll
    for (int ks = 0; ks < 8; ++ks)
        afr[ks] = *(const short8*)(A + (size_t)(m0+lc)*256 + ks*32 + lg*8);

    const f32x4 zf = {0.f,0.f,0.f,0.f};
    f32x4 acc[16];
    #pragma unroll
    for (int ct = 0; ct < 16; ++ct) acc[ct] = zf;

    #pragma unroll
    for (int ct = 0; ct < 16; ++ct) {
        #pragma unroll
        for (int ks = 0; ks < 8; ++ks) {
            const short8 bfr = *(const short8*)(W + (size_t)(ct*16+lc)*256 + ks*32 + lg*8);
            acc[ct] = __builtin_amdgcn_mfma_f32_16x16x32_bf16(afr[ks], bfr, acc[ct], 0, 0, 0);
        }
    }

    // epilogue: acc[ct][r] = C[m0 + 4lg + r][16ct + lc]
    #pragma unroll
    for (int ct = 0; ct < 16; ++ct) {
        const int cc = ct*16 + lc;
        float bias = 0.f;
        if (z == 0) bias = bq[cc];
        else if (z == 1) bias = bk[cc];
        else if (z == 2) bias = bv[cc];
        #pragma unroll
        for (int r = 0; r < 4; ++r) {
            const size_t idx = (size_t)(m0 + 4*lg + r)*DMODEL + cc;
            const short v = f2bf(acc[ct][r] + bias);
            if (z == 0)      q[idx]    = v;
            else if (z == 1) kb[idx]   = v;
            else if (z == 2) vbuf[idx] = v;
            else             pbuf[idx] = v;
        }
    }
}

// ---------------- fp32 GEMM core (128x128 tile, 8x8 micro) — out-proj only ----------------
__device__ __forceinline__ void gemm_core(const float* __restrict__ A,
                                          const float* __restrict__ W,
                                          int row0, int col0, float acc[8][8]) {
    __shared__ float As[8][136];
    __shared__ float Ws[8][136];
    const int t  = threadIdx.x;
    const int tx = t & 15, ty = t >> 4;
    #pragma unroll
    for (int i = 0; i < 8; ++i)
        #pragma unroll
        for (int j = 0; j < 8; ++j) acc[i][j] = 0.f;

    const int ar = t >> 1, ac4 = t & 1;
    const int wr = t >> 5, wc4 = t & 31;

    for (int k0 = 0; k0 < 256; k0 += 8) {
        float4 av = *(const float4*)(A + (size_t)(row0+ar)*256 + k0 + ac4*4);
        As[ac4*4+0][ar] = av.x;
        As[ac4*4+1][ar] = av.y;
        As[ac4*4+2][ar] = av.z;
        As[ac4*4+3][ar] = av.w;
        *(float4*)&Ws[wr][wc4*4] = *(const float4*)(W + (size_t)(k0+wr)*256 + col0 + wc4*4);
        __syncthreads();
        #pragma unroll
        for (int kk = 0; kk < 8; ++kk) {
            float a8[8], b8[8];
            *(float4*)&a8[0] = *(const float4*)&As[kk][ty*8];
            *(float4*)&a8[4] = *(const float4*)&As[kk][ty*8+4];
            *(float4*)&b8[0] = *(const float4*)&Ws[kk][tx*8];
            *(float4*)&b8[4] = *(const float4*)&Ws[kk][tx*8+4];
            #pragma unroll
            for (int i = 0; i < 8; ++i)
                #pragma unroll
                for (int j = 0; j < 8; ++j)
                    acc[i][j] += a8[i]*b8[j];
        }
        __syncthreads();
    }
}

__global__ __launch_bounds__(256)
void gemm_kernel(const float* __restrict__ A, const float* __restrict__ W,
                 const float* __restrict__ bias, float* __restrict__ C, int M) {
    const int row0 = blockIdx.x * 128;
    if (row0 >= M) return;
    const int col0 = blockIdx.y * 128;
    float acc[8][8];
    gemm_core(A, W, row0, col0, acc);
    const int t = threadIdx.x;
    const int tx = t & 15, ty = t >> 4;
    #pragma unroll
    for (int i = 0; i < 8; ++i) {
        const int rr = row0 + ty*8 + i;
        #pragma unroll
        for (int j4 = 0; j4 < 2; ++j4) {
            const int cc = col0 + tx*8 + j4*4;
            float4 o;
            o.x = acc[i][j4*4+0] + bias[cc+0];
            o.y = acc[i][j4*4+1] + bias[cc+1];
            o.z = acc[i][j4*4+2] + bias[cc+2];
            o.w = acc[i][j4*4+3] + bias[cc+3];
            *(float4*)(C + (size_t)rr*256 + cc) = o;
        }
    }
}

// ---------------- V transpose: v[b,l,h,d] -> vT[b,h,d,l] ----------------
__global__ __launch_bounds__(256)
void vtrans_kernel(const short* __restrict__ v, short* __restrict__ vT) {
    const int l0 = blockIdx.x * 64;
    const int h  = blockIdx.y;
    const int b  = blockIdx.z;
    const int t  = threadIdx.x;
    __shared__ short s[32][72];
    const int r = t & 63, c8 = (t >> 6) * 8;
    short8 val = *(const short8*)(v + ((size_t)(b*L_SEQ + l0 + r))*DMODEL + h*DHEAD + c8);
    #pragma unroll
    for (int j = 0; j < 8; ++j) s[c8+j][r] = val[j];
    __syncthreads();
    const int d = t >> 3, l8 = (t & 7) * 8;
    *(short8*)(vT + (((size_t)((b*NH + h)*DHEAD + d))*L_SEQ) + l0 + l8) = *(const short8*)&s[d][l8];
}

// ---------------- fused MFMA attention, swapped-operand, BARRIER-FREE ----------------
// Same structure as round 5 (wave-private sT/sPk, no __syncthreads). Changes:
// __launch_bounds__(256,3) so the ~90-reg fragment set fits WITHOUT spilling
// (round 5's (256,4) forced VGPR=64 -> 13MB scratch spill traffic); q stored once,
// u/v biases added in registers at fragment setup (saves the qv buffer + loads).
__global__ __launch_bounds__(256, 3)
void attn_mfma_kernel(const short* __restrict__ qg, const short* __restrict__ kb,
                      const short* __restrict__ pb, const short* __restrict__ vT,
                      const float* __restrict__ ub, const float* __restrict__ vb,
                      float* __restrict__ ctx) {
    const int q0 = blockIdx.x * 64;
    const int h  = blockIdx.y;
    const int b  = blockIdx.z;
    const int t  = threadIdx.x;
    const int w  = t >> 6;
    const int l  = t & 63;
    const int lc = l & 15;
    const int lg = l >> 4;

    __shared__ float    sT[4][17][84];  // per-wave: rows 0..15 = T[16w+lc], row 16 = boundary
    __shared__ unsigned sPk[64][32];    // P bf16-pairs, XOR-swizzled; reused as ctx tile

    // fragment setup: one q load per row + in-register bias adds
    const size_t qrow = ((size_t)(b*L_SEQ + q0 + 16*w + lc))*DMODEL + h*DHEAD + lg*8;
    const short8 qraw = *(const short8*)(qg + qrow);
    short8 qraw_sh = zero8();
    {
        const int r2 = q0 + 16*w + lc + 1;
        if (r2 < L_SEQ)
            qraw_sh = *(const short8*)(qg + ((size_t)(b*L_SEQ + r2))*DMODEL + h*DHEAD + lg*8);
    }
    short8 aqu, aqv, aqv_sh;
    #pragma unroll
    for (int j = 0; j < 8; ++j) {
        const float u_ = ub[h*DHEAD + lg*8 + j];
        const float v_ = vb[h*DHEAD + lg*8 + j];
        const float f  = bf2f(qraw[j]);
        aqu[j]    = f2bf(f + u_);
        aqv[j]    = f2bf(f + v_);
        aqv_sh[j] = f2bf(bf2f(qraw_sh[j]) + v_);
    }

    float m_r = -3.0e38f, l_r = 0.f;
    f32x4 acc0 = {0.f,0.f,0.f,0.f}, acc1 = {0.f,0.f,0.f,0.f};

    const short* kbase = kb + ((size_t)(b*L_SEQ))*DMODEL + h*DHEAD;
    const short* pbase = pb + h*DHEAD;
    const short* vbase = vT + ((size_t)((b*NH + h)*DHEAD))*L_SEQ;
    const f32x4 zf = {0.f, 0.f, 0.f, 0.f};
    const float KSC = 0.0625f * 1.44269504088896340736f;  // (1/16)*log2(e)

    // ptilde loader for wave-window slot cc at tile k0n: A-row jj = 16*(cc+3-w)+lc
    auto loadP = [&](int k0n, int cc) -> short8 {
        const int rho = (k0n - q0 - 65) + 16*(cc + 3 - w) + lc;
        if (rho == -1) return zero8();
        const int pr = rho + (rho < 0 ? (L_SEQ+1) : 0);
        return *(const short8*)(pbase + (size_t)pr*DMODEL + lg*8);
    };

    // persistent A-fragments
    short8 kfrag[4], pfrag[5];
    #pragma unroll
    for (int ct = 0; ct < 4; ++ct)
        kfrag[ct] = *(const short8*)(kbase + (size_t)(ct*16 + lc)*DMODEL + lg*8);
    #pragma unroll
    for (int cc = 0; cc < 5; ++cc) pfrag[cc] = loadP(0, cc);

    const int qi   = 16*w + lc;
    const int colc = 4*lg + 15 - lc;     // gather col = 16*ct + colc + r
    const int swkey = lc & 7;

    for (int k0 = 0; k0 < L_SEQ; k0 += 64) {
        const int diff = k0 - q0;

        // ---- content: S^T tiles (A = K, B = Qu) ----
        f32x4 cts[4];
        #pragma unroll
        for (int ct = 0; ct < 4; ++ct)
            cts[ct] = __builtin_amdgcn_mfma_f32_16x16x32_bf16(kfrag[ct], aqu, zf, 0, 0, 0);

        // ---- pos band: unshifted (rows lc) + shifted (boundary row 16, lc==15 lanes) ----
        #pragma unroll
        for (int cc = 0; cc < 5; ++cc) {
            f32x4 tt = __builtin_amdgcn_mfma_f32_16x16x32_bf16(pfrag[cc], aqv, zf, 0, 0, 0);
            *(f32x4*)&sT[w][lc][16*cc + 4*lg] = tt;
            f32x4 tt2 = __builtin_amdgcn_mfma_f32_16x16x32_bf16(pfrag[cc], aqv_sh, zf, 0, 0, 0);
            if (lc == 15) *(f32x4*)&sT[w][16][16*cc + 4*lg] = tt2;
        }

        // ---- rotate p-window (slide 64 = 4 slots) + prefetch next tile ----
        pfrag[0] = pfrag[4];
        if (k0 + 64 < L_SEQ) {
            #pragma unroll
            for (int ct = 0; ct < 4; ++ct)
                kfrag[ct] = *(const short8*)(kbase + (size_t)(k0 + 64 + ct*16 + lc)*DMODEL + lg*8);
            #pragma unroll
            for (int cc = 1; cc < 5; ++cc) pfrag[cc] = loadP(k0 + 64, cc);
        }
        // V fragments for the CURRENT tile (consumed after softmax)
        short8 vfrag[2][2];
        #pragma unroll
        for (int dt = 0; dt < 2; ++dt)
            #pragma unroll
            for (int kc = 0; kc < 2; ++kc)
                vfrag[dt][kc] = *(const short8*)(vbase + (size_t)(16*dt + lc)*L_SEQ + k0 + kc*32 + lg*8);

        asm volatile("s_waitcnt lgkmcnt(0)" ::: "memory");  // sT writes visible (intra-wave)

        // ---- rel-shift gather + combine: read sT[w][lc+up][16ct+colc+r] ----
        float sc[4][4];
        const int cthr = 17 - diff + 16*w;   // up = (col >= cthr)
        if (cthr > 78) {
            const float* rowp = &sT[w][lc][0];
            #pragma unroll
            for (int ct = 0; ct < 4; ++ct)
                #pragma unroll
                for (int r = 0; r < 4; ++r)
                    sc[ct][r] = (cts[ct][r] + rowp[16*ct + colc + r]) * KSC;
        } else if (cthr <= 0) {
            const float* rowp = &sT[w][lc+1][0];
            #pragma unroll
            for (int ct = 0; ct < 4; ++ct)
                #pragma unroll
                for (int r = 0; r < 4; ++r)
                    sc[ct][r] = (cts[ct][r] + rowp[16*ct + colc + r]) * KSC;
        } else {
            #pragma unroll
            for (int ct = 0; ct < 4; ++ct)
                #pragma unroll
                for (int r = 0; r < 4; ++r) {
                    const int col = 16*ct + colc + r;
                    const int up = (col >= cthr) ? 1 : 0;
                    sc[ct][r] = (cts[ct][r] + sT[w][lc + up][col]) * KSC;
                }
        }

        // ---- softmax: lane owns row qi; in-reg reduce + 2 shfls ----
        float mx = sc[0][0];
        #pragma unroll
        for (int ct = 0; ct < 4; ++ct)
            #pragma unroll
            for (int r = 0; r < 4; ++r) mx = fmaxf(mx, sc[ct][r]);
        mx = fmaxf(mx, __shfl_xor(mx, 16));
        mx = fmaxf(mx, __shfl_xor(mx, 32));
        const float mn = fmaxf(m_r, mx);
        float ts = 0.f;
        #pragma unroll
        for (int ct = 0; ct < 4; ++ct)
            #pragma unroll
            for (int r = 0; r < 4; ++r) { sc[ct][r] = exp2f(sc[ct][r] - mn); ts += sc[ct][r]; }
        ts += __shfl_xor(ts, 16);
        ts += __shfl_xor(ts, 32);
        const float alpha = exp2f(m_r - mn);
        m_r = mn;
        l_r = l_r*alpha + ts;

        // ---- pack P -> sPk (bf16 pairs, XOR-block swizzle; wave-private rows) ----
        #pragma unroll
        for (int ct = 0; ct < 4; ++ct) {
            unsigned lo, hi;
            asm("v_cvt_pk_bf16_f32 %0, %1, %2" : "=v"(lo) : "v"(sc[ct][0]), "v"(sc[ct][1]));
            asm("v_cvt_pk_bf16_f32 %0, %1, %2" : "=v"(hi) : "v"(sc[ct][2]), "v"(sc[ct][3]));
            const int kbi = 2*ct + (lg >> 1);
            const int idx = ((kbi ^ swkey) << 2) + 2*(lg & 1);
            *(uint2*)&sPk[qi][idx] = make_uint2(lo, hi);
        }
        #pragma unroll
        for (int r = 0; r < 4; ++r) { acc0[r] *= alpha; acc1[r] *= alpha; }

        asm volatile("s_waitcnt lgkmcnt(0)" ::: "memory");  // sPk writes visible (intra-wave)

        // ---- PV: ctx^T += V^T . P ----
        #pragma unroll
        for (int kc = 0; kc < 2; ++kc) {
            const int idx = ((4*kc + lg) ^ swkey) << 2;
            const short8 bp = *(const short8*)&sPk[qi][idx];
            acc0 = __builtin_amdgcn_mfma_f32_16x16x32_bf16(vfrag[0][kc], bp, acc0, 0, 0, 0);
            acc1 = __builtin_amdgcn_mfma_f32_16x16x32_bf16(vfrag[1][kc], bp, acc1, 0, 0, 0);
        }
    }

    // ---- epilogue: transpose ctx^T -> ctx through sPk space (wave-private rows) ----
    asm volatile("s_waitcnt lgkmcnt(0)" ::: "memory");
    float* sCt = (float*)&sPk[0][0];   // [64][32] f32 view
    const float inv = 1.f / l_r;
    {
        f32x4 o0, o1;
        #pragma unroll
        for (int r = 0; r < 4; ++r) { o0[r] = acc0[r]*inv; o1[r] = acc1[r]*inv; }
        *(f32x4*)&sCt[qi*32 + 4*lg]      = o0;
        *(f32x4*)&sCt[qi*32 + 16 + 4*lg] = o1;
    }
    asm volatile("s_waitcnt lgkmcnt(0)" ::: "memory");
    const int rr = 16*w + (l >> 2);
    const int c0 = (l & 3) * 8;
    float4 o0 = *(float4*)&sCt[rr*32 + c0];
    float4 o1 = *(float4*)&sCt[rr*32 + c0 + 4];
    float* orow = ctx + ((size_t)(b*L_SEQ + q0 + rr))*DMODEL + h*DHEAD + c0;
    *(float4*)orow     = o0;
    *(float4*)(orow+4) = o1;
}

extern "C" void kernel_launch(void* const* d_in, const int* in_sizes, int n_in,
                              void* d_out, int out_size, void* d_ws, size_t ws_size,
                              hipStream_t stream) {
    (void)in_sizes; (void)n_in; (void)out_size; (void)ws_size;
    const float* x     = (const float*)d_in[0];
    const float* gamma = (const float*)d_in[1];
    const float* beta  = (const float*)d_in[2];
    const float* Wq    = (const float*)d_in[3];
    const float* bq    = (const float*)d_in[4];
    const float* Wk    = (const float*)d_in[5];
    const float* bk    = (const float*)d_in[6];
    const float* Wv    = (const float*)d_in[7];
    const float* bv    = (const float*)d_in[8];
    const float* Wp    = (const float*)d_in[9];
    const float* ub    = (const float*)d_in[10];
    const float* vb    = (const float*)d_in[11];
    const float* Wo    = (const float*)d_in[12];
    const float* bo    = (const float*)d_in[13];
    float* out = (float*)d_out;

    char* wsb = (char*)d_ws;
    float* ctx = (float*)wsb;                                    // 8 MB f32
    short* xnb = (short*)(wsb + 8388608);                        // 4 MB bf16
    short* peb = (short*)(wsb + 8388608 + 4194304);              // 1 MB bf16
    short* WT  = (short*)(wsb + 8388608 + 4194304 + 1048576);    // 512 KB bf16 (4 mats)
    short* q   = WT  + (size_t)4*65536;                          // 4 MB
    short* kbf = q   + (size_t)NROW*DMODEL;                      // 4 MB
    short* vbf = kbf + (size_t)NROW*DMODEL;                      // 4 MB
    short* vT  = vbf + (size_t)NROW*DMODEL;                      // 4 MB
    short* pbf = vT  + (size_t)NROW*DMODEL;                      // 1 MB

    pe_kernel<<<1024, 256, 0, stream>>>(peb);
    ln_kernel<<<2048, 256, 0, stream>>>(x, gamma, beta, xnb);
    wcvt_kernel<<<dim3(4,4,4), 256, 0, stream>>>(Wq, Wk, Wv, Wp, WT);
    projmm_kernel<<<416, 256, 0, stream>>>(xnb, peb, WT, bq, bk, bv, q, kbf, vbf, pbf);
    vtrans_kernel<<<dim3(32,8,4), 256, 0, stream>>>(vbf, vT);
    attn_mfma_kernel<<<dim3(32,8,4), 256, 0, stream>>>(q, kbf, pbf, vT, ub, vb, ctx);
    gemm_kernel<<<dim3(64,2,1), 256, 0, stream>>>(ctx, Wo, bo, out, NROW);
}